// Round 2
// baseline (402.016 us; speedup 1.0000x reference)
//
#include <hip/hip_runtime.h>
#include <hip/hip_fp16.h>

// MHA with softmax over HEADS axis. R2: occupancy fixes everywhere.
// - QKV proj merged into one grid.z=3 dispatch (384 blocks vs 3x128 serial)
// - attn_denom retiled to 32x64 per block (2048 blocks = 100% occ cap)
// - attn_ctx j-split x4 (2048 blocks), IDn loaded as f16x8 in A-layout
//   (E=exp(s) round-trips LDS instead of P), fp32 atomic ctx accumulation
// - out GEMM split-K x2 with fp32 atomicAdd into zeroed d_out

typedef _Float16 f16;
typedef _Float16 f16x4 __attribute__((ext_vector_type(4)));
typedef _Float16 f16x8 __attribute__((ext_vector_type(8)));
typedef float    f32x4 __attribute__((ext_vector_type(4)));

#define S_LEN 2048
#define DIM   1024
#define NH    16
#define DK    64
#define SCALE 0.125f

#define MFMA(a, b, c) __builtin_amdgcn_mfma_f32_16x16x32_f16(a, b, c, 0, 0, 0)

typedef __attribute__((address_space(1))) void g_void;
typedef __attribute__((address_space(3))) void l_void;

static __device__ __forceinline__ void gload_lds16(const void* g, void* l) {
  __builtin_amdgcn_global_load_lds((g_void*)g, (l_void*)l, 16, 0, 0);
}

// ---------------------------------------------------------------- cvt fp32->f16
__global__ __launch_bounds__(256) void cvt_f32_f16(const float* __restrict__ src,
                                                   f16* __restrict__ dst, int n4) {
  int i = blockIdx.x * 256 + threadIdx.x;
  if (i < n4) {
    float4 v = ((const float4*)src)[i];
    f16x4 o = {(f16)v.x, (f16)v.y, (f16)v.z, (f16)v.w};
    ((f16x4*)dst)[i] = o;
  }
}

// batched variant: 3 equal-size buffers (q,k,v), grid.y selects
__global__ __launch_bounds__(256) void cvt3(const float* __restrict__ s0, const float* __restrict__ s1,
                                            const float* __restrict__ s2, f16* __restrict__ d0,
                                            f16* __restrict__ d1, f16* __restrict__ d2, int n4) {
  int z = blockIdx.y;
  const float* src = z == 0 ? s0 : z == 1 ? s1 : s2;
  f16* dst = z == 0 ? d0 : z == 1 ? d1 : d2;
  int i = blockIdx.x * 256 + threadIdx.x;
  if (i < n4) {
    float4 v = ((const float4*)src)[i];
    f16x4 o = {(f16)v.x, (f16)v.y, (f16)v.z, (f16)v.w};
    ((f16x4*)dst)[i] = o;
  }
}

__global__ __launch_bounds__(256) void cvt4(const float* __restrict__ s0, const float* __restrict__ s1,
                                            const float* __restrict__ s2, const float* __restrict__ s3,
                                            f16* __restrict__ d0, f16* __restrict__ d1,
                                            f16* __restrict__ d2, f16* __restrict__ d3, int n4) {
  int z = blockIdx.y;
  const float* src = z == 0 ? s0 : z == 1 ? s1 : z == 2 ? s2 : s3;
  f16* dst = z == 0 ? d0 : z == 1 ? d1 : z == 2 ? d2 : d3;
  int i = blockIdx.x * 256 + threadIdx.x;
  if (i < n4) {
    float4 v = ((const float4*)src)[i];
    f16x4 o = {(f16)v.x, (f16)v.y, (f16)v.z, (f16)v.w};
    ((f16x4*)dst)[i] = o;
  }
}

// ---------------------------------------------------------------- GEMM core
// C(128x128 tile) = X @ W^T ; X:(M,1024) f16, W:(N,1024) f16, both row-major.
// 4 waves, each 64x64. K range [k0,k1).
static __device__ __forceinline__ void gemm_core(const f16* __restrict__ X,
                                                 const f16* __restrict__ W,
                                                 int k0, int k1, int bm, int bn,
                                                 f16* As, f16* Bs,
                                                 f32x4 (&acc)[4][4]) {
  const int tid = threadIdx.x;
  const int wv = tid >> 6;
  const int lane = tid & 63;
  const int qd = lane >> 4;
  const int l16 = lane & 15;
  const int wm = (wv & 1) * 64;
  const int wn = (wv >> 1) * 64;

  const int srow = wv * 32 + (lane >> 2);
  const int skcol = (lane & 3) * 8;
  const f16* gA = X + (size_t)(bm + srow) * DIM + k0 + skcol;
  const f16* gB = W + (size_t)(bn + srow) * DIM + k0 + skcol;
  f16* lA = &As[(wv * 32) * 32];
  f16* lB = &Bs[(wv * 32) * 32];

  for (int kt = k0; kt < k1; kt += 32) {
    gload_lds16(gA, lA);
    gload_lds16(gA + 16 * DIM, lA + 16 * 32);
    gload_lds16(gB, lB);
    gload_lds16(gB + 16 * DIM, lB + 16 * 32);
    gA += 32;
    gB += 32;
    __syncthreads();

    f16x8 af[4], bf[4];
#pragma unroll
    for (int mi = 0; mi < 4; mi++)
      af[mi] = *(const f16x8*)&As[(wm + mi * 16 + l16) * 32 + qd * 8];
#pragma unroll
    for (int ni = 0; ni < 4; ni++)
      bf[ni] = *(const f16x8*)&Bs[(wn + ni * 16 + l16) * 32 + qd * 8];
#pragma unroll
    for (int mi = 0; mi < 4; mi++)
#pragma unroll
      for (int ni = 0; ni < 4; ni++)
        acc[mi][ni] = MFMA(af[mi], bf[ni], acc[mi][ni]);
    __syncthreads();
  }
}

// ---------------------------------------------------------------- merged QKV proj
// z=0: Qp = qh@Wq^T+bq (row-major); z=1: Kp; z=2: Vt = (vh@Wv^T+bv)^T
__global__ __launch_bounds__(256) void gemm_qkv(
    const f16* __restrict__ X0, const f16* __restrict__ X1, const f16* __restrict__ X2,
    const f16* __restrict__ W0, const f16* __restrict__ W1, const f16* __restrict__ W2,
    const float* __restrict__ b0, const float* __restrict__ b1, const float* __restrict__ b2,
    f16* __restrict__ o0, f16* __restrict__ o1, f16* __restrict__ o2) {
  __shared__ __align__(16) f16 As[128 * 32];
  __shared__ __align__(16) f16 Bs[128 * 32];
  const int z = blockIdx.z;
  const f16* X = z == 0 ? X0 : z == 1 ? X1 : X2;
  const f16* W = z == 0 ? W0 : z == 1 ? W1 : W2;
  const float* bias = z == 0 ? b0 : z == 1 ? b1 : b2;
  f16* outh = z == 0 ? o0 : z == 1 ? o1 : o2;

  const int bm = blockIdx.y * 128, bn = blockIdx.x * 128;
  f32x4 acc[4][4];
#pragma unroll
  for (int a = 0; a < 4; a++)
#pragma unroll
    for (int b = 0; b < 4; b++) acc[a][b] = (f32x4){0.f, 0.f, 0.f, 0.f};

  gemm_core(X, W, 0, DIM, bm, bn, As, Bs, acc);

  const int tid = threadIdx.x;
  const int wv = tid >> 6, lane = tid & 63;
  const int qd = lane >> 4, l16 = lane & 15;
  const int wm = (wv & 1) * 64, wn = (wv >> 1) * 64;
#pragma unroll
  for (int mi = 0; mi < 4; mi++) {
#pragma unroll
    for (int ni = 0; ni < 4; ni++) {
      const int gm = bm + wm + mi * 16 + qd * 4;
      const int gn = bn + wn + ni * 16 + l16;
      const float bs = bias[gn];
      if (z == 2) {
        f16x4 o = {(f16)(acc[mi][ni][0] + bs), (f16)(acc[mi][ni][1] + bs),
                   (f16)(acc[mi][ni][2] + bs), (f16)(acc[mi][ni][3] + bs)};
        *(f16x4*)&outh[(size_t)gn * S_LEN + gm] = o;  // Vt[d][j]
      } else {
#pragma unroll
        for (int r = 0; r < 4; r++)
          outh[(size_t)(gm + r) * DIM + gn] = (f16)(acc[mi][ni][r] + bs);
      }
    }
  }
}

// ---------------------------------------------------------------- out GEMM, split-K x2
__global__ __launch_bounds__(256) void gemm_out(const f16* __restrict__ X,
                                                const f16* __restrict__ W,
                                                const float* __restrict__ bias,
                                                float* __restrict__ outf) {
  __shared__ __align__(16) f16 As[128 * 32];
  __shared__ __align__(16) f16 Bs[128 * 32];
  const int z = blockIdx.z;  // K half
  const int bm = blockIdx.y * 128, bn = blockIdx.x * 128;
  f32x4 acc[4][4];
#pragma unroll
  for (int a = 0; a < 4; a++)
#pragma unroll
    for (int b = 0; b < 4; b++) acc[a][b] = (f32x4){0.f, 0.f, 0.f, 0.f};

  gemm_core(X, W, z * (DIM / 2), (z + 1) * (DIM / 2), bm, bn, As, Bs, acc);

  const int tid = threadIdx.x;
  const int wv = tid >> 6, lane = tid & 63;
  const int qd = lane >> 4, l16 = lane & 15;
  const int wm = (wv & 1) * 64, wn = (wv >> 1) * 64;
#pragma unroll
  for (int mi = 0; mi < 4; mi++) {
#pragma unroll
    for (int ni = 0; ni < 4; ni++) {
      const int gm = bm + wm + mi * 16 + qd * 4;
      const int gn = bn + wn + ni * 16 + l16;
      const float bs = z == 0 ? bias[gn] : 0.f;
#pragma unroll
      for (int r = 0; r < 4; r++)
        atomicAdd(&outf[(size_t)(gm + r) * DIM + gn], acc[mi][ni][r] + bs);
    }
  }
}

// ---------------------------------------------------------------- pass A: IDn = 1/sum_h exp
// block = 4 waves: wv&1 -> 16-row i half, wv>>1 -> 32-col j half. 32x64 per block.
// grid (S/64, S/32) = 2048 blocks -> 100% occupancy cap.
__global__ __launch_bounds__(256) void attn_denom(const f16* __restrict__ Qp,
                                                  const f16* __restrict__ Kp,
                                                  f16* __restrict__ IDn) {
  const int tid = threadIdx.x;
  const int wv = tid >> 6;
  const int lane = tid & 63;
  const int qd = lane >> 4;
  const int l16 = lane & 15;
  const int ib = blockIdx.y * 32 + (wv & 1) * 16;
  const int jb = blockIdx.x * 64 + (wv >> 1) * 32;

  float dsum[2][4];
#pragma unroll
  for (int ni = 0; ni < 2; ni++)
#pragma unroll
    for (int r = 0; r < 4; r++) dsum[ni][r] = 0.f;

  for (int h = 0; h < NH; h++) {
    f16x8 aq[2], bk[2][2];
#pragma unroll
    for (int kk = 0; kk < 2; kk++)
      aq[kk] = *(const f16x8*)(Qp + (size_t)(ib + l16) * DIM + h * DK + kk * 32 + qd * 8);
#pragma unroll
    for (int ni = 0; ni < 2; ni++)
#pragma unroll
      for (int kk = 0; kk < 2; kk++)
        bk[ni][kk] = *(const f16x8*)(Kp + (size_t)(jb + ni * 16 + l16) * DIM +
                                     h * DK + kk * 32 + qd * 8);
#pragma unroll
    for (int ni = 0; ni < 2; ni++) {
      f32x4 s = {0.f, 0.f, 0.f, 0.f};
      s = MFMA(aq[0], bk[ni][0], s);  // same order as attn_ctx -> bit-identical
      s = MFMA(aq[1], bk[ni][1], s);
#pragma unroll
      for (int r = 0; r < 4; r++) dsum[ni][r] += __expf(s[r] * SCALE);
    }
  }
#pragma unroll
  for (int ni = 0; ni < 2; ni++)
#pragma unroll
    for (int r = 0; r < 4; r++) {
      const int gi = ib + qd * 4 + r;
      const int gj = jb + ni * 16 + l16;
      IDn[(size_t)gi * S_LEN + gj] = (f16)(1.f / dsum[ni][r]);
    }
}

// ---------------------------------------------------------------- pass B: ctx, j-split x4
// grid (S/64, NH, 4). Wave: 16 Q rows of one head, j-range S/4, fp32 atomic ctx.
// E=exp(s) goes through LDS (C->A layout); IDn vector-loaded in A-layout.
__global__ __launch_bounds__(256) void attn_ctx(const f16* __restrict__ Qp,
                                                const f16* __restrict__ Kp,
                                                const f16* __restrict__ Vt,
                                                const f16* __restrict__ IDn,
                                                float* __restrict__ Cp) {
  __shared__ __align__(16) f16 El[4][16 * 32];
  const int tid = threadIdx.x;
  const int wv = tid >> 6;
  const int lane = tid & 63;
  const int qd = lane >> 4;
  const int l16 = lane & 15;
  const int h = blockIdx.y;
  const int ib = blockIdx.x * 64 + wv * 16;
  const int jbase = blockIdx.z * (S_LEN / 4);
  f16* el = El[wv];

  f16x8 aq[2];
#pragma unroll
  for (int kk = 0; kk < 2; kk++)
    aq[kk] = *(const f16x8*)(Qp + (size_t)(ib + l16) * DIM + h * DK + kk * 32 + qd * 8);

  f32x4 cacc[4];
#pragma unroll
  for (int nd = 0; nd < 4; nd++) cacc[nd] = (f32x4){0.f, 0.f, 0.f, 0.f};

  for (int jj = 0; jj < S_LEN / 4; jj += 32) {
    const int j0 = jbase + jj;
#pragma unroll
    for (int ni = 0; ni < 2; ni++) {
      f16x8 bk0 = *(const f16x8*)(Kp + (size_t)(j0 + ni * 16 + l16) * DIM + h * DK + qd * 8);
      f16x8 bk1 = *(const f16x8*)(Kp + (size_t)(j0 + ni * 16 + l16) * DIM + h * DK + 32 + qd * 8);
      f32x4 s = {0.f, 0.f, 0.f, 0.f};
      s = MFMA(aq[0], bk0, s);  // same accumulation order as attn_denom
      s = MFMA(aq[1], bk1, s);
#pragma unroll
      for (int r = 0; r < 4; r++)
        el[(qd * 4 + r) * 32 + ni * 16 + l16] = (f16)__expf(s[r] * SCALE);
    }
    // wave-private LDS round trip: C-layout -> A-layout (in-order per wave)
    f16x8 ef = *(const f16x8*)&el[l16 * 32 + qd * 8];
    f16x8 idn = *(const f16x8*)&IDn[(size_t)(ib + l16) * S_LEN + j0 + qd * 8];
    f16x8 p = ef * idn;
#pragma unroll
    for (int nd = 0; nd < 4; nd++) {
      f16x8 bv = *(const f16x8*)(Vt + (size_t)(h * DK + nd * 16 + l16) * S_LEN + j0 + qd * 8);
      cacc[nd] = MFMA(p, bv, cacc[nd]);
    }
  }
#pragma unroll
  for (int nd = 0; nd < 4; nd++)
#pragma unroll
    for (int r = 0; r < 4; r++)
      atomicAdd(&Cp[(size_t)(ib + qd * 4 + r) * DIM + h * DK + nd * 16 + l16], cacc[nd][r]);
}

// ---------------------------------------------------------------- launcher
extern "C" void kernel_launch(void* const* d_in, const int* in_sizes, int n_in,
                              void* d_out, int out_size, void* d_ws, size_t ws_size,
                              hipStream_t stream) {
  const float* q  = (const float*)d_in[0];
  const float* k  = (const float*)d_in[1];
  const float* v  = (const float*)d_in[2];
  const float* Wq = (const float*)d_in[3];
  const float* bq = (const float*)d_in[4];
  const float* Wk = (const float*)d_in[5];
  const float* bk = (const float*)d_in[6];
  const float* Wv = (const float*)d_in[7];
  const float* bv = (const float*)d_in[8];
  const float* Wo = (const float*)d_in[9];
  const float* bo = (const float*)d_in[10];
  float* out = (float*)d_out;

  // ws layout (f16), 32 MB total. Aliases (stream-ordered, all safe):
  //   IDn (S*S f16, 8MB) over qh+kh      [dead after gemm_qkv]
  //   Cp  (S*DIM f32, 8MB) over vh+wqh+wkh [dead after gemm_qkv]
  //   Ct  (S*DIM f16, 4MB) over qh        [IDn dead after attn_ctx]
  f16* w = (f16*)d_ws;
  f16* qh  = w;                          // S*DIM
  f16* kh  = qh + (size_t)S_LEN * DIM;
  f16* vh  = kh + (size_t)S_LEN * DIM;
  f16* wqh = vh + (size_t)S_LEN * DIM;   // DIM*DIM
  f16* wkh = wqh + (size_t)DIM * DIM;
  f16* wvh = wkh + (size_t)DIM * DIM;
  f16* woh = wvh + (size_t)DIM * DIM;
  f16* Qp  = woh + (size_t)DIM * DIM;    // S*DIM
  f16* Kp  = Qp + (size_t)S_LEN * DIM;
  f16* Vt  = Kp + (size_t)S_LEN * DIM;   // DIM*S
  f16* IDn = qh;
  float* Cp = (float*)vh;
  f16* Ct  = qh;

  const int nqkv4 = S_LEN * DIM / 4, nw4 = DIM * DIM / 4;
  dim3 b256(256);
  cvt3<<<dim3(nqkv4 / 256, 3), b256, 0, stream>>>(q, k, v, qh, kh, vh, nqkv4);
  cvt4<<<dim3(nw4 / 256, 4), b256, 0, stream>>>(Wq, Wk, Wv, Wo, wqh, wkh, wvh, woh, nw4);

  gemm_qkv<<<dim3(DIM / 128, S_LEN / 128, 3), b256, 0, stream>>>(
      qh, kh, vh, wqh, wkh, wvh, bq, bk, bv, Qp, Kp, Vt);

  hipMemsetAsync(Cp, 0, (size_t)S_LEN * DIM * sizeof(float), stream);
  hipMemsetAsync(out, 0, (size_t)S_LEN * DIM * sizeof(float), stream);

  attn_denom<<<dim3(S_LEN / 64, S_LEN / 32), b256, 0, stream>>>(Qp, Kp, IDn);
  attn_ctx<<<dim3(S_LEN / 64, NH, 4), b256, 0, stream>>>(Qp, Kp, Vt, IDn, Cp);

  cvt_f32_f16<<<nqkv4 / 256, b256, 0, stream>>>(Cp, Ct, nqkv4);

  gemm_out<<<dim3(DIM / 128, S_LEN / 128, 2), b256, 0, stream>>>(Ct, woh, bo, out);
}

// Round 3
// 254.713 us; speedup vs baseline: 1.5783x; 1.5783x over previous
//
#include <hip/hip_runtime.h>
#include <hip/hip_fp16.h>

// MHA with softmax over HEADS axis. R3: kill the L1-miss-path bottleneck.
// All shared streams (K, V, IDn) now staged through LDS via global_load_lds
// (streaming DMA path, shared across the block's 4 waves) instead of per-wave
// register-return loads; tiles enlarged so cachelines amortize over MFMAs.

typedef _Float16 f16;
typedef _Float16 f16x4 __attribute__((ext_vector_type(4)));
typedef _Float16 f16x8 __attribute__((ext_vector_type(8)));
typedef float    f32x4 __attribute__((ext_vector_type(4)));

#define S_LEN 2048
#define DIM   1024
#define NH    16
#define DK    64
#define SCALE 0.125f

#define MFMA(a, b, c) __builtin_amdgcn_mfma_f32_16x16x32_f16(a, b, c, 0, 0, 0)

typedef __attribute__((address_space(1))) void g_void;
typedef __attribute__((address_space(3))) void l_void;

static __device__ __forceinline__ void gload_lds16(const void* g, void* l) {
  // global ptr is per-lane; LDS dst = wave-uniform base + lane*16
  __builtin_amdgcn_global_load_lds((g_void*)g, (l_void*)l, 16, 0, 0);
}

// ---------------------------------------------------------------- cvt fp32->f16
__global__ __launch_bounds__(256) void cvt_f32_f16(const float* __restrict__ src,
                                                   f16* __restrict__ dst, int n4) {
  int i = blockIdx.x * 256 + threadIdx.x;
  if (i < n4) {
    float4 v = ((const float4*)src)[i];
    f16x4 o = {(f16)v.x, (f16)v.y, (f16)v.z, (f16)v.w};
    ((f16x4*)dst)[i] = o;
  }
}

__global__ __launch_bounds__(256) void cvt3(const float* __restrict__ s0, const float* __restrict__ s1,
                                            const float* __restrict__ s2, f16* __restrict__ d0,
                                            f16* __restrict__ d1, f16* __restrict__ d2, int n4) {
  int z = blockIdx.y;
  const float* src = z == 0 ? s0 : z == 1 ? s1 : s2;
  f16* dst = z == 0 ? d0 : z == 1 ? d1 : d2;
  int i = blockIdx.x * 256 + threadIdx.x;
  if (i < n4) {
    float4 v = ((const float4*)src)[i];
    f16x4 o = {(f16)v.x, (f16)v.y, (f16)v.z, (f16)v.w};
    ((f16x4*)dst)[i] = o;
  }
}

__global__ __launch_bounds__(256) void cvt4(const float* __restrict__ s0, const float* __restrict__ s1,
                                            const float* __restrict__ s2, const float* __restrict__ s3,
                                            f16* __restrict__ d0, f16* __restrict__ d1,
                                            f16* __restrict__ d2, f16* __restrict__ d3, int n4) {
  int z = blockIdx.y;
  const float* src = z == 0 ? s0 : z == 1 ? s1 : z == 2 ? s2 : s3;
  f16* dst = z == 0 ? d0 : z == 1 ? d1 : z == 2 ? d2 : d3;
  int i = blockIdx.x * 256 + threadIdx.x;
  if (i < n4) {
    float4 v = ((const float4*)src)[i];
    f16x4 o = {(f16)v.x, (f16)v.y, (f16)v.z, (f16)v.w};
    ((f16x4*)dst)[i] = o;
  }
}

// ---------------------------------------------------------------- GEMM core (m97 style)
static __device__ __forceinline__ void gemm_core(const f16* __restrict__ X,
                                                 const f16* __restrict__ W,
                                                 int k0, int k1, int bm, int bn,
                                                 f16* As, f16* Bs,
                                                 f32x4 (&acc)[4][4]) {
  const int tid = threadIdx.x;
  const int wv = tid >> 6;
  const int lane = tid & 63;
  const int qd = lane >> 4;
  const int l16 = lane & 15;
  const int wm = (wv & 1) * 64;
  const int wn = (wv >> 1) * 64;

  const int srow = wv * 32 + (lane >> 2);
  const int skcol = (lane & 3) * 8;
  const f16* gA = X + (size_t)(bm + srow) * DIM + k0 + skcol;
  const f16* gB = W + (size_t)(bn + srow) * DIM + k0 + skcol;
  f16* lA = &As[(wv * 32) * 32];
  f16* lB = &Bs[(wv * 32) * 32];

  for (int kt = k0; kt < k1; kt += 32) {
    gload_lds16(gA, lA);
    gload_lds16(gA + 16 * DIM, lA + 16 * 32);
    gload_lds16(gB, lB);
    gload_lds16(gB + 16 * DIM, lB + 16 * 32);
    gA += 32;
    gB += 32;
    __syncthreads();

    f16x8 af[4], bf[4];
#pragma unroll
    for (int mi = 0; mi < 4; mi++)
      af[mi] = *(const f16x8*)&As[(wm + mi * 16 + l16) * 32 + qd * 8];
#pragma unroll
    for (int ni = 0; ni < 4; ni++)
      bf[ni] = *(const f16x8*)&Bs[(wn + ni * 16 + l16) * 32 + qd * 8];
#pragma unroll
    for (int mi = 0; mi < 4; mi++)
#pragma unroll
      for (int ni = 0; ni < 4; ni++)
        acc[mi][ni] = MFMA(af[mi], bf[ni], acc[mi][ni]);
    __syncthreads();
  }
}

// ---------------------------------------------------------------- merged QKV proj
__global__ __launch_bounds__(256) void gemm_qkv(
    const f16* __restrict__ X0, const f16* __restrict__ X1, const f16* __restrict__ X2,
    const f16* __restrict__ W0, const f16* __restrict__ W1, const f16* __restrict__ W2,
    const float* __restrict__ b0, const float* __restrict__ b1, const float* __restrict__ b2,
    f16* __restrict__ o0, f16* __restrict__ o1, f16* __restrict__ o2) {
  __shared__ __align__(16) f16 As[128 * 32];
  __shared__ __align__(16) f16 Bs[128 * 32];
  const int z = blockIdx.z;
  const f16* X = z == 0 ? X0 : z == 1 ? X1 : X2;
  const f16* W = z == 0 ? W0 : z == 1 ? W1 : W2;
  const float* bias = z == 0 ? b0 : z == 1 ? b1 : b2;
  f16* outh = z == 0 ? o0 : z == 1 ? o1 : o2;

  const int bm = blockIdx.y * 128, bn = blockIdx.x * 128;
  f32x4 acc[4][4];
#pragma unroll
  for (int a = 0; a < 4; a++)
#pragma unroll
    for (int b = 0; b < 4; b++) acc[a][b] = (f32x4){0.f, 0.f, 0.f, 0.f};

  gemm_core(X, W, 0, DIM, bm, bn, As, Bs, acc);

  const int tid = threadIdx.x;
  const int wv = tid >> 6, lane = tid & 63;
  const int qd = lane >> 4, l16 = lane & 15;
  const int wm = (wv & 1) * 64, wn = (wv >> 1) * 64;
#pragma unroll
  for (int mi = 0; mi < 4; mi++) {
#pragma unroll
    for (int ni = 0; ni < 4; ni++) {
      const int gm = bm + wm + mi * 16 + qd * 4;
      const int gn = bn + wn + ni * 16 + l16;
      const float bs = bias[gn];
      if (z == 2) {
        f16x4 o = {(f16)(acc[mi][ni][0] + bs), (f16)(acc[mi][ni][1] + bs),
                   (f16)(acc[mi][ni][2] + bs), (f16)(acc[mi][ni][3] + bs)};
        *(f16x4*)&outh[(size_t)gn * S_LEN + gm] = o;  // Vt[d][j]
      } else {
#pragma unroll
        for (int r = 0; r < 4; r++)
          outh[(size_t)(gm + r) * DIM + gn] = (f16)(acc[mi][ni][r] + bs);
      }
    }
  }
}

// ---------------------------------------------------------------- out GEMM, split-K x2
__global__ __launch_bounds__(256) void gemm_out(const f16* __restrict__ X,
                                                const f16* __restrict__ W,
                                                const float* __restrict__ bias,
                                                float* __restrict__ outf) {
  __shared__ __align__(16) f16 As[128 * 32];
  __shared__ __align__(16) f16 Bs[128 * 32];
  const int z = blockIdx.z;
  const int bm = blockIdx.y * 128, bn = blockIdx.x * 128;
  f32x4 acc[4][4];
#pragma unroll
  for (int a = 0; a < 4; a++)
#pragma unroll
    for (int b = 0; b < 4; b++) acc[a][b] = (f32x4){0.f, 0.f, 0.f, 0.f};

  gemm_core(X, W, z * (DIM / 2), (z + 1) * (DIM / 2), bm, bn, As, Bs, acc);

  const int tid = threadIdx.x;
  const int wv = tid >> 6, lane = tid & 63;
  const int qd = lane >> 4, l16 = lane & 15;
  const int wm = (wv & 1) * 64, wn = (wv >> 1) * 64;
#pragma unroll
  for (int mi = 0; mi < 4; mi++) {
#pragma unroll
    for (int ni = 0; ni < 4; ni++) {
      const int gm = bm + wm + mi * 16 + qd * 4;
      const int gn = bn + wn + ni * 16 + l16;
      const float bs = z == 0 ? bias[gn] : 0.f;
#pragma unroll
      for (int r = 0; r < 4; r++)
        atomicAdd(&outf[(size_t)(gm + r) * DIM + gn], acc[mi][ni][r] + bs);
    }
  }
}

// ---------------------------------------------------------------- pass A: IDn = 1/sum_h exp
// GEMM-shaped: block = 128(i) x 128(j), grid (16,16). Per h: two staged k-slices
// (kk=0,1) -> 16 MFMA each; dsum accumulated per-lane in registers (heads are
// register-local by construction). Same MFMA order as attn_ctx -> bit-identical s.
__global__ __launch_bounds__(256) void attn_denom(const f16* __restrict__ Qp,
                                                  const f16* __restrict__ Kp,
                                                  f16* __restrict__ IDn) {
  __shared__ __align__(16) f16 Qs[128 * 32];
  __shared__ __align__(16) f16 Ks2[128 * 32];
  const int tid = threadIdx.x;
  const int wv = tid >> 6;
  const int lane = tid & 63;
  const int qd = lane >> 4;
  const int l16 = lane & 15;
  const int wm = (wv & 1) * 64, wn = (wv >> 1) * 64;
  const int bi = blockIdx.y * 128, bj = blockIdx.x * 128;
  const int lr4 = lane >> 2, lc4 = lane & 3;

  f32x4 dsum[4][4];
#pragma unroll
  for (int a = 0; a < 4; a++)
#pragma unroll
    for (int b = 0; b < 4; b++) dsum[a][b] = (f32x4){0.f, 0.f, 0.f, 0.f};

  for (int h = 0; h < NH; h++) {
    f32x4 s[4][4];
#pragma unroll
    for (int a = 0; a < 4; a++)
#pragma unroll
      for (int b = 0; b < 4; b++) s[a][b] = (f32x4){0.f, 0.f, 0.f, 0.f};

    for (int kk = 0; kk < 2; kk++) {
#pragma unroll
      for (int t = 0; t < 2; t++) {
        const int row = wv * 32 + t * 16;
        gload_lds16(Qp + (size_t)(bi + row + lr4) * DIM + h * DK + kk * 32 + lc4 * 8,
                    Qs + row * 32);
        gload_lds16(Kp + (size_t)(bj + row + lr4) * DIM + h * DK + kk * 32 + lc4 * 8,
                    Ks2 + row * 32);
      }
      __syncthreads();
      f16x8 af[4], bf[4];
#pragma unroll
      for (int mi = 0; mi < 4; mi++)
        af[mi] = *(const f16x8*)&Qs[(wm + mi * 16 + l16) * 32 + qd * 8];
#pragma unroll
      for (int ni = 0; ni < 4; ni++)
        bf[ni] = *(const f16x8*)&Ks2[(wn + ni * 16 + l16) * 32 + qd * 8];
#pragma unroll
      for (int mi = 0; mi < 4; mi++)
#pragma unroll
        for (int ni = 0; ni < 4; ni++)
          s[mi][ni] = MFMA(af[mi], bf[ni], s[mi][ni]);  // kk=0 then kk=1: same order as ctx
      __syncthreads();
    }
#pragma unroll
    for (int mi = 0; mi < 4; mi++)
#pragma unroll
      for (int ni = 0; ni < 4; ni++)
#pragma unroll
        for (int r = 0; r < 4; r++)
          dsum[mi][ni][r] += __expf(s[mi][ni][r] * SCALE);
  }
#pragma unroll
  for (int mi = 0; mi < 4; mi++)
#pragma unroll
    for (int ni = 0; ni < 4; ni++)
#pragma unroll
      for (int r = 0; r < 4; r++) {
        const int gi = bi + wm + mi * 16 + qd * 4 + r;
        const int gj = bj + wn + ni * 16 + l16;
        IDn[(size_t)gi * S_LEN + gj] = (f16)(1.f / dsum[mi][ni][r]);
      }
}

// ---------------------------------------------------------------- pass B: ctx
// grid (S/256, NH, 4). Block: i-tile 256 (wave = 64 rows), one head, j-range 512.
// Per j-iter: stage K(32x64) + Vt(64x32) + IDn(256x32) via global_load_lds (24KB,
// shared by 4 waves), then per wave 16 QK-MFMA + exp + LDS P-transpose + 16 PV-MFMA.
__global__ __launch_bounds__(256) void attn_ctx(const f16* __restrict__ Qp,
                                                const f16* __restrict__ Kp,
                                                const f16* __restrict__ Vt,
                                                const f16* __restrict__ IDn,
                                                float* __restrict__ Cp) {
  __shared__ __align__(16) f16 Ks[32 * 64];    // [j][k]
  __shared__ __align__(16) f16 Vs[64 * 32];    // [d][j]
  __shared__ __align__(16) f16 Is[256 * 32];   // [i][j]
  __shared__ __align__(16) f16 Pl[4][64 * 32]; // per-wave P scratch
  const int tid = threadIdx.x;
  const int wv = tid >> 6;
  const int lane = tid & 63;
  const int qd = lane >> 4;
  const int l16 = lane & 15;
  const int h = blockIdx.y;
  const int i0 = blockIdx.x * 256;
  const int iw = i0 + wv * 64;
  const int jb = blockIdx.z * 512;
  const int lr8 = lane >> 3, lc8 = lane & 7;
  const int lr4 = lane >> 2, lc4 = lane & 3;
  f16* pl = Pl[wv];

  // persistent Q A-frags: 4 mi x 2 kk (one-time global loads)
  f16x8 aq[4][2];
#pragma unroll
  for (int mi = 0; mi < 4; mi++)
#pragma unroll
    for (int kk = 0; kk < 2; kk++)
      aq[mi][kk] = *(const f16x8*)(Qp + (size_t)(iw + mi * 16 + l16) * DIM +
                                   h * DK + kk * 32 + qd * 8);

  f32x4 acc[4][4];
#pragma unroll
  for (int a = 0; a < 4; a++)
#pragma unroll
    for (int b = 0; b < 4; b++) acc[a][b] = (f32x4){0.f, 0.f, 0.f, 0.f};

  for (int jt = 0; jt < 16; jt++) {
    const int j0 = jb + jt * 32;
    // ---- stage (6 DMA insts per wave, 24KB per block-iter)
    gload_lds16(Kp + (size_t)(j0 + wv * 8 + lr8) * DIM + h * DK + lc8 * 8,
                Ks + (wv * 8) * 64);
    gload_lds16(Vt + (size_t)(h * DK + wv * 16 + lr4) * S_LEN + j0 + lc4 * 8,
                Vs + (wv * 16) * 32);
#pragma unroll
    for (int t = 0; t < 4; t++) {
      const int row = (wv * 4 + t) * 16;
      gload_lds16(IDn + (size_t)(i0 + row + lr4) * S_LEN + j0 + lc4 * 8,
                  Is + row * 32);
    }
    __syncthreads();

    // ---- QK^T -> exp -> Pl (C-layout)
    f16x8 bk[2][2];
#pragma unroll
    for (int ni = 0; ni < 2; ni++)
#pragma unroll
      for (int kk = 0; kk < 2; kk++)
        bk[ni][kk] = *(const f16x8*)&Ks[(ni * 16 + l16) * 64 + kk * 32 + qd * 8];
#pragma unroll
    for (int mi = 0; mi < 4; mi++)
#pragma unroll
      for (int ni = 0; ni < 2; ni++) {
        f32x4 s = {0.f, 0.f, 0.f, 0.f};
        s = MFMA(aq[mi][0], bk[ni][0], s);  // same order as attn_denom
        s = MFMA(aq[mi][1], bk[ni][1], s);
#pragma unroll
        for (int r = 0; r < 4; r++)
          pl[(mi * 16 + qd * 4 + r) * 32 + ni * 16 + l16] = (f16)__expf(s[r] * SCALE);
      }

    // ---- P (A-layout) * IDn, then PV
    f16x8 bv[4];
#pragma unroll
    for (int nd = 0; nd < 4; nd++)
      bv[nd] = *(const f16x8*)&Vs[(nd * 16 + l16) * 32 + qd * 8];
#pragma unroll
    for (int mi = 0; mi < 4; mi++) {
      f16x8 ef = *(const f16x8*)&pl[(mi * 16 + l16) * 32 + qd * 8];  // wave-private
      f16x8 idn = *(const f16x8*)&Is[(wv * 64 + mi * 16 + l16) * 32 + qd * 8];
      f16x8 p = ef * idn;
#pragma unroll
      for (int nd = 0; nd < 4; nd++)
        acc[mi][nd] = MFMA(p, bv[nd], acc[mi][nd]);
    }
    __syncthreads();
  }

#pragma unroll
  for (int mi = 0; mi < 4; mi++)
#pragma unroll
    for (int nd = 0; nd < 4; nd++)
#pragma unroll
      for (int r = 0; r < 4; r++)
        atomicAdd(&Cp[(size_t)(iw + mi * 16 + qd * 4 + r) * DIM + h * DK + nd * 16 + l16],
                  acc[mi][nd][r]);
}

// ---------------------------------------------------------------- launcher
extern "C" void kernel_launch(void* const* d_in, const int* in_sizes, int n_in,
                              void* d_out, int out_size, void* d_ws, size_t ws_size,
                              hipStream_t stream) {
  const float* q  = (const float*)d_in[0];
  const float* k  = (const float*)d_in[1];
  const float* v  = (const float*)d_in[2];
  const float* Wq = (const float*)d_in[3];
  const float* bq = (const float*)d_in[4];
  const float* Wk = (const float*)d_in[5];
  const float* bk = (const float*)d_in[6];
  const float* Wv = (const float*)d_in[7];
  const float* bv = (const float*)d_in[8];
  const float* Wo = (const float*)d_in[9];
  const float* bo = (const float*)d_in[10];
  float* out = (float*)d_out;

  // ws layout (32 MB). Aliases (stream-ordered): IDn over qh+kh [dead after
  // gemm_qkv]; Cp (fp32 8MB) over vh+wqh+wkh [dead after gemm_qkv]; Ct over qh
  // [IDn dead after attn_ctx]. woh (needed by gemm_out) is NOT aliased.
  f16* w = (f16*)d_ws;
  f16* qh  = w;                          // 0..4MB
  f16* kh  = qh + (size_t)S_LEN * DIM;   // 4..8
  f16* vh  = kh + (size_t)S_LEN * DIM;   // 8..12
  f16* wqh = vh + (size_t)S_LEN * DIM;   // 12..14
  f16* wkh = wqh + (size_t)DIM * DIM;    // 14..16
  f16* wvh = wkh + (size_t)DIM * DIM;    // 16..18
  f16* woh = wvh + (size_t)DIM * DIM;    // 18..20
  f16* Qp  = woh + (size_t)DIM * DIM;    // 20..24
  f16* Kp  = Qp + (size_t)S_LEN * DIM;   // 24..28
  f16* Vt  = Kp + (size_t)S_LEN * DIM;   // 28..32
  f16* IDn = qh;                         // 0..8MB
  float* Cp = (float*)vh;                // 8..16MB
  f16* Ct  = qh;                         // 0..4MB

  const int nqkv4 = S_LEN * DIM / 4, nw4 = DIM * DIM / 4;
  dim3 b256(256);
  cvt3<<<dim3(nqkv4 / 256, 3), b256, 0, stream>>>(q, k, v, qh, kh, vh, nqkv4);
  cvt4<<<dim3(nw4 / 256, 4), b256, 0, stream>>>(Wq, Wk, Wv, Wo, wqh, wkh, wvh, woh, nw4);

  gemm_qkv<<<dim3(DIM / 128, S_LEN / 128, 3), b256, 0, stream>>>(
      qh, kh, vh, wqh, wkh, wvh, bq, bk, bv, Qp, Kp, Vt);

  hipMemsetAsync(Cp, 0, (size_t)S_LEN * DIM * sizeof(float), stream);
  hipMemsetAsync(out, 0, (size_t)S_LEN * DIM * sizeof(float), stream);

  attn_denom<<<dim3(S_LEN / 128, S_LEN / 128), b256, 0, stream>>>(Qp, Kp, IDn);
  attn_ctx<<<dim3(S_LEN / 256, NH, 4), b256, 0, stream>>>(Qp, Kp, Vt, IDn, Cp);

  cvt_f32_f16<<<nqkv4 / 256, b256, 0, stream>>>(Cp, Ct, nqkv4);

  gemm_out<<<dim3(DIM / 128, S_LEN / 128, 2), b256, 0, stream>>>(Ct, woh, bo, out);
}

// Round 4
// 235.419 us; speedup vs baseline: 1.7077x; 1.0820x over previous
//
#include <hip/hip_runtime.h>
#include <hip/hip_fp16.h>

// MHA with softmax over HEADS axis. R4: parallelism everywhere (>=3-4 blocks/CU)
// + conflict-free 64B-stride LDS layouts (K staged as [kk][j][32] slices).
// attn_ctx: i-tile 128, grid 1024; attn_denom: 64x64 tiles, grid 1024;
// gemm_qkv: 128x64 tiles, grid 768; gemm_out: 128x64 + splitK2, grid 512.

typedef _Float16 f16;
typedef _Float16 f16x4 __attribute__((ext_vector_type(4)));
typedef _Float16 f16x8 __attribute__((ext_vector_type(8)));
typedef float    f32x4 __attribute__((ext_vector_type(4)));

#define S_LEN 2048
#define DIM   1024
#define NH    16
#define DK    64
#define SCALE 0.125f

#define MFMA(a, b, c) __builtin_amdgcn_mfma_f32_16x16x32_f16(a, b, c, 0, 0, 0)

typedef __attribute__((address_space(1))) void g_void;
typedef __attribute__((address_space(3))) void l_void;

static __device__ __forceinline__ void gload_lds16(const void* g, void* l) {
  // async global->LDS DMA; LDS dst wave-uniform base + lane*16 (1KB per inst)
  __builtin_amdgcn_global_load_lds((g_void*)g, (l_void*)l, 16, 0, 0);
}

// ---------------------------------------------------------------- cvt fp32->f16
__global__ __launch_bounds__(256) void cvt_f32_f16(const float* __restrict__ src,
                                                   f16* __restrict__ dst, int n4) {
  int i = blockIdx.x * 256 + threadIdx.x;
  if (i < n4) {
    float4 v = ((const float4*)src)[i];
    f16x4 o = {(f16)v.x, (f16)v.y, (f16)v.z, (f16)v.w};
    ((f16x4*)dst)[i] = o;
  }
}

__global__ __launch_bounds__(256) void cvt3(const float* __restrict__ s0, const float* __restrict__ s1,
                                            const float* __restrict__ s2, f16* __restrict__ d0,
                                            f16* __restrict__ d1, f16* __restrict__ d2, int n4) {
  int z = blockIdx.y;
  const float* src = z == 0 ? s0 : z == 1 ? s1 : s2;
  f16* dst = z == 0 ? d0 : z == 1 ? d1 : d2;
  int i = blockIdx.x * 256 + threadIdx.x;
  if (i < n4) {
    float4 v = ((const float4*)src)[i];
    f16x4 o = {(f16)v.x, (f16)v.y, (f16)v.z, (f16)v.w};
    ((f16x4*)dst)[i] = o;
  }
}

__global__ __launch_bounds__(256) void cvt4(const float* __restrict__ s0, const float* __restrict__ s1,
                                            const float* __restrict__ s2, const float* __restrict__ s3,
                                            f16* __restrict__ d0, f16* __restrict__ d1,
                                            f16* __restrict__ d2, f16* __restrict__ d3, int n4) {
  int z = blockIdx.y;
  const float* src = z == 0 ? s0 : z == 1 ? s1 : z == 2 ? s2 : s3;
  f16* dst = z == 0 ? d0 : z == 1 ? d1 : z == 2 ? d2 : d3;
  int i = blockIdx.x * 256 + threadIdx.x;
  if (i < n4) {
    float4 v = ((const float4*)src)[i];
    f16x4 o = {(f16)v.x, (f16)v.y, (f16)v.z, (f16)v.w};
    ((f16x4*)dst)[i] = o;
  }
}

// ---------------------------------------------------------------- 128x64 GEMM core
// C tile = X(128 rows) @ W^T(64 cols). 4 waves 2x2, wave tile 64x32.
// acc[4][2]; K range [k0,k1).
static __device__ __forceinline__ void gemm64_core(const f16* __restrict__ X,
                                                   const f16* __restrict__ W,
                                                   int k0, int k1, int bm, int bn,
                                                   f16* As, f16* Bs,
                                                   f32x4 (&acc)[4][2]) {
  const int tid = threadIdx.x;
  const int wv = tid >> 6;
  const int lane = tid & 63;
  const int qd = lane >> 4;
  const int l16 = lane & 15;
  const int wm = (wv & 1) * 64;
  const int wn = (wv >> 1) * 32;
  const int lr4 = lane >> 2, lc4 = lane & 3;

  const f16* gA = X + (size_t)(bm + wv * 32 + lr4) * DIM + k0 + lc4 * 8;
  const f16* gB = W + (size_t)(bn + wv * 16 + lr4) * DIM + k0 + lc4 * 8;
  f16* lA = &As[(wv * 32) * 32];
  f16* lB = &Bs[(wv * 16) * 32];

  for (int kt = k0; kt < k1; kt += 32) {
    gload_lds16(gA, lA);
    gload_lds16(gA + 16 * DIM, lA + 16 * 32);
    gload_lds16(gB, lB);
    gA += 32;
    gB += 32;
    __syncthreads();

    f16x8 af[4], bf[2];
#pragma unroll
    for (int mi = 0; mi < 4; mi++)
      af[mi] = *(const f16x8*)&As[(wm + mi * 16 + l16) * 32 + qd * 8];
#pragma unroll
    for (int ni = 0; ni < 2; ni++)
      bf[ni] = *(const f16x8*)&Bs[(wn + ni * 16 + l16) * 32 + qd * 8];
#pragma unroll
    for (int mi = 0; mi < 4; mi++)
#pragma unroll
      for (int ni = 0; ni < 2; ni++)
        acc[mi][ni] = MFMA(af[mi], bf[ni], acc[mi][ni]);
    __syncthreads();
  }
}

// ---------------------------------------------------------------- merged QKV proj
// grid (DIM/64, S/128, 3). z=0: Qp; z=1: Kp; z=2: Vt (transposed)
__global__ __launch_bounds__(256) void gemm_qkv(
    const f16* __restrict__ X0, const f16* __restrict__ X1, const f16* __restrict__ X2,
    const f16* __restrict__ W0, const f16* __restrict__ W1, const f16* __restrict__ W2,
    const float* __restrict__ b0, const float* __restrict__ b1, const float* __restrict__ b2,
    f16* __restrict__ o0, f16* __restrict__ o1, f16* __restrict__ o2) {
  __shared__ __align__(16) f16 As[128 * 32];
  __shared__ __align__(16) f16 Bs[64 * 32];
  const int z = blockIdx.z;
  const f16* X = z == 0 ? X0 : z == 1 ? X1 : X2;
  const f16* W = z == 0 ? W0 : z == 1 ? W1 : W2;
  const float* bias = z == 0 ? b0 : z == 1 ? b1 : b2;
  f16* outh = z == 0 ? o0 : z == 1 ? o1 : o2;

  const int bm = blockIdx.y * 128, bn = blockIdx.x * 64;
  f32x4 acc[4][2];
#pragma unroll
  for (int a = 0; a < 4; a++)
#pragma unroll
    for (int b = 0; b < 2; b++) acc[a][b] = (f32x4){0.f, 0.f, 0.f, 0.f};

  gemm64_core(X, W, 0, DIM, bm, bn, As, Bs, acc);

  const int tid = threadIdx.x;
  const int wv = tid >> 6, lane = tid & 63;
  const int qd = lane >> 4, l16 = lane & 15;
  const int wm = (wv & 1) * 64, wn = (wv >> 1) * 32;
#pragma unroll
  for (int mi = 0; mi < 4; mi++) {
#pragma unroll
    for (int ni = 0; ni < 2; ni++) {
      const int gm = bm + wm + mi * 16 + qd * 4;
      const int gn = bn + wn + ni * 16 + l16;
      const float bs = bias[gn];
      if (z == 2) {
        f16x4 o = {(f16)(acc[mi][ni][0] + bs), (f16)(acc[mi][ni][1] + bs),
                   (f16)(acc[mi][ni][2] + bs), (f16)(acc[mi][ni][3] + bs)};
        *(f16x4*)&outh[(size_t)gn * S_LEN + gm] = o;  // Vt[d][j]
      } else {
#pragma unroll
        for (int r = 0; r < 4; r++)
          outh[(size_t)(gm + r) * DIM + gn] = (f16)(acc[mi][ni][r] + bs);
      }
    }
  }
}

// ---------------------------------------------------------------- out GEMM 128x64, splitK2
// grid (DIM/64, S/128, 2)
__global__ __launch_bounds__(256) void gemm_out(const f16* __restrict__ X,
                                                const f16* __restrict__ W,
                                                const float* __restrict__ bias,
                                                float* __restrict__ outf) {
  __shared__ __align__(16) f16 As[128 * 32];
  __shared__ __align__(16) f16 Bs[64 * 32];
  const int z = blockIdx.z;
  const int bm = blockIdx.y * 128, bn = blockIdx.x * 64;
  f32x4 acc[4][2];
#pragma unroll
  for (int a = 0; a < 4; a++)
#pragma unroll
    for (int b = 0; b < 2; b++) acc[a][b] = (f32x4){0.f, 0.f, 0.f, 0.f};

  gemm64_core(X, W, z * (DIM / 2), (z + 1) * (DIM / 2), bm, bn, As, Bs, acc);

  const int tid = threadIdx.x;
  const int wv = tid >> 6, lane = tid & 63;
  const int qd = lane >> 4, l16 = lane & 15;
  const int wm = (wv & 1) * 64, wn = (wv >> 1) * 32;
#pragma unroll
  for (int mi = 0; mi < 4; mi++) {
#pragma unroll
    for (int ni = 0; ni < 2; ni++) {
      const int gm = bm + wm + mi * 16 + qd * 4;
      const int gn = bn + wn + ni * 16 + l16;
      const float bs = z == 0 ? bias[gn] : 0.f;
#pragma unroll
      for (int r = 0; r < 4; r++)
        atomicAdd(&outf[(size_t)(gm + r) * DIM + gn], acc[mi][ni][r] + bs);
    }
  }
}

// ---------------------------------------------------------------- pass A: IDn = 1/sum_h exp
// 64x64 tile per block, grid (S/64, S/64) = 1024 blocks. Per h: stage full
// 64-wide head slice as two [kk][row][32] slices (64B rows, conflict-free),
// one barrier pair per head; dsum per-lane in registers.
__global__ __launch_bounds__(256) void attn_denom(const f16* __restrict__ Qp,
                                                  const f16* __restrict__ Kp,
                                                  f16* __restrict__ IDn) {
  __shared__ __align__(16) f16 Qs[2][64 * 32];
  __shared__ __align__(16) f16 Ks[2][64 * 32];
  const int tid = threadIdx.x;
  const int wv = tid >> 6;
  const int lane = tid & 63;
  const int qd = lane >> 4;
  const int l16 = lane & 15;
  const int wm = (wv & 1) * 32, wn = (wv >> 1) * 32;
  const int bi = blockIdx.y * 64, bj = blockIdx.x * 64;
  const int lr4 = lane >> 2, lc4 = lane & 3;
  const int kkw = wv & 1;          // staging: wave's kk slice
  const int rw = (wv >> 1) * 32;   // staging: wave's row range

  f32x4 dsum[2][2];
#pragma unroll
  for (int a = 0; a < 2; a++)
#pragma unroll
    for (int b = 0; b < 2; b++) dsum[a][b] = (f32x4){0.f, 0.f, 0.f, 0.f};

  for (int h = 0; h < NH; h++) {
    const f16* gq = Qp + (size_t)(bi + rw + lr4) * DIM + h * DK + kkw * 32 + lc4 * 8;
    const f16* gk = Kp + (size_t)(bj + rw + lr4) * DIM + h * DK + kkw * 32 + lc4 * 8;
    gload_lds16(gq, &Qs[kkw][rw * 32]);
    gload_lds16(gq + 16 * DIM, &Qs[kkw][(rw + 16) * 32]);
    gload_lds16(gk, &Ks[kkw][rw * 32]);
    gload_lds16(gk + 16 * DIM, &Ks[kkw][(rw + 16) * 32]);
    __syncthreads();

    f16x8 af[2][2], bf[2][2];
#pragma unroll
    for (int mi = 0; mi < 2; mi++)
#pragma unroll
      for (int kk = 0; kk < 2; kk++)
        af[mi][kk] = *(const f16x8*)&Qs[kk][(wm + mi * 16 + l16) * 32 + qd * 8];
#pragma unroll
    for (int ni = 0; ni < 2; ni++)
#pragma unroll
      for (int kk = 0; kk < 2; kk++)
        bf[ni][kk] = *(const f16x8*)&Ks[kk][(wn + ni * 16 + l16) * 32 + qd * 8];
#pragma unroll
    for (int mi = 0; mi < 2; mi++)
#pragma unroll
      for (int ni = 0; ni < 2; ni++) {
        f32x4 s = {0.f, 0.f, 0.f, 0.f};
        s = MFMA(af[mi][0], bf[ni][0], s);  // kk order identical to attn_ctx
        s = MFMA(af[mi][1], bf[ni][1], s);
#pragma unroll
        for (int r = 0; r < 4; r++) dsum[mi][ni][r] += __expf(s[r] * SCALE);
      }
    __syncthreads();
  }
#pragma unroll
  for (int mi = 0; mi < 2; mi++)
#pragma unroll
    for (int ni = 0; ni < 2; ni++)
#pragma unroll
      for (int r = 0; r < 4; r++) {
        const int gi = bi + wm + mi * 16 + qd * 4 + r;
        const int gj = bj + wn + ni * 16 + l16;
        IDn[(size_t)gi * S_LEN + gj] = (f16)(1.f / dsum[mi][ni][r]);
      }
}

// ---------------------------------------------------------------- pass B: ctx
// grid (S/128, NH, 4). Block: i-tile 128 (wave = 32 rows), one head, j-range 512.
// LDS 24KB -> 4 blocks/CU at grid 1024. K staged as [kk][j][32] (64B rows).
__global__ __launch_bounds__(256) void attn_ctx(const f16* __restrict__ Qp,
                                                const f16* __restrict__ Kp,
                                                const f16* __restrict__ Vt,
                                                const f16* __restrict__ IDn,
                                                float* __restrict__ Cp) {
  __shared__ __align__(16) f16 Ks[2][32 * 32];  // [kk][j][k32]
  __shared__ __align__(16) f16 Vs[64 * 32];     // [d][j]
  __shared__ __align__(16) f16 Is[128 * 32];    // [i][j]
  __shared__ __align__(16) f16 Pl[4][32 * 32];  // per-wave P scratch
  const int tid = threadIdx.x;
  const int wv = tid >> 6;
  const int lane = tid & 63;
  const int qd = lane >> 4;
  const int l16 = lane & 15;
  const int h = blockIdx.y;
  const int i0 = blockIdx.x * 128;
  const int iw = i0 + wv * 32;
  const int jb = blockIdx.z * 512;
  const int lr4 = lane >> 2, lc4 = lane & 3;
  f16* pl = Pl[wv];

  // persistent Q A-frags (one-time loads, amortized over 16 j-iters)
  f16x8 aq[2][2];
#pragma unroll
  for (int mi = 0; mi < 2; mi++)
#pragma unroll
    for (int kk = 0; kk < 2; kk++)
      aq[mi][kk] = *(const f16x8*)(Qp + (size_t)(iw + mi * 16 + l16) * DIM +
                                   h * DK + kk * 32 + qd * 8);

  f32x4 acc[2][4];
#pragma unroll
  for (int a = 0; a < 2; a++)
#pragma unroll
    for (int b = 0; b < 4; b++) acc[a][b] = (f32x4){0.f, 0.f, 0.f, 0.f};

  for (int jt = 0; jt < 16; jt++) {
    const int j0 = jb + jt * 32;
    // ---- stage 16KB: 4 DMA per wave
    gload_lds16(Kp + (size_t)(j0 + (wv >> 1) * 16 + lr4) * DIM + h * DK + (wv & 1) * 32 + lc4 * 8,
                &Ks[wv & 1][((wv >> 1) * 16) * 32]);
    gload_lds16(Vt + (size_t)(h * DK + wv * 16 + lr4) * S_LEN + j0 + lc4 * 8,
                &Vs[(wv * 16) * 32]);
#pragma unroll
    for (int t = 0; t < 2; t++) {
      const int row = (wv * 2 + t) * 16;
      gload_lds16(IDn + (size_t)(i0 + row + lr4) * S_LEN + j0 + lc4 * 8,
                  &Is[row * 32]);
    }
    __syncthreads();

    // ---- QK^T -> exp -> Pl (C-layout)
    f16x8 bk[2][2];
#pragma unroll
    for (int ni = 0; ni < 2; ni++)
#pragma unroll
      for (int kk = 0; kk < 2; kk++)
        bk[ni][kk] = *(const f16x8*)&Ks[kk][(ni * 16 + l16) * 32 + qd * 8];
#pragma unroll
    for (int mi = 0; mi < 2; mi++)
#pragma unroll
      for (int ni = 0; ni < 2; ni++) {
        f32x4 s = {0.f, 0.f, 0.f, 0.f};
        s = MFMA(aq[mi][0], bk[ni][0], s);  // same order as attn_denom
        s = MFMA(aq[mi][1], bk[ni][1], s);
#pragma unroll
        for (int r = 0; r < 4; r++)
          pl[(mi * 16 + qd * 4 + r) * 32 + ni * 16 + l16] = (f16)__expf(s[r] * SCALE);
      }

    // ---- P(A-layout) * IDn, then PV
    f16x8 bv[4];
#pragma unroll
    for (int nd = 0; nd < 4; nd++)
      bv[nd] = *(const f16x8*)&Vs[(nd * 16 + l16) * 32 + qd * 8];
#pragma unroll
    for (int mi = 0; mi < 2; mi++) {
      f16x8 ef = *(const f16x8*)&pl[(mi * 16 + l16) * 32 + qd * 8];  // wave-private
      f16x8 idn = *(const f16x8*)&Is[(wv * 32 + mi * 16 + l16) * 32 + qd * 8];
      f16x8 p = ef * idn;
#pragma unroll
      for (int nd = 0; nd < 4; nd++)
        acc[mi][nd] = MFMA(p, bv[nd], acc[mi][nd]);
    }
    __syncthreads();
  }

#pragma unroll
  for (int mi = 0; mi < 2; mi++)
#pragma unroll
    for (int nd = 0; nd < 4; nd++)
#pragma unroll
      for (int r = 0; r < 4; r++)
        atomicAdd(&Cp[(size_t)(iw + mi * 16 + qd * 4 + r) * DIM + h * DK + nd * 16 + l16],
                  acc[mi][nd][r]);
}

// ---------------------------------------------------------------- launcher
extern "C" void kernel_launch(void* const* d_in, const int* in_sizes, int n_in,
                              void* d_out, int out_size, void* d_ws, size_t ws_size,
                              hipStream_t stream) {
  const float* q  = (const float*)d_in[0];
  const float* k  = (const float*)d_in[1];
  const float* v  = (const float*)d_in[2];
  const float* Wq = (const float*)d_in[3];
  const float* bq = (const float*)d_in[4];
  const float* Wk = (const float*)d_in[5];
  const float* bk = (const float*)d_in[6];
  const float* Wv = (const float*)d_in[7];
  const float* bv = (const float*)d_in[8];
  const float* Wo = (const float*)d_in[9];
  const float* bo = (const float*)d_in[10];
  float* out = (float*)d_out;

  // ws layout (32 MB). Aliases (stream-ordered): IDn over qh+kh [dead after
  // gemm_qkv]; Cp (fp32 8MB) over vh+wqh+wkh [dead after gemm_qkv]; Ct over qh
  // region 0..4MB is free again only after ctx -- use woh-safe region: Ct over
  // qh (IDn rows 0..) is NOT safe until ctx done; cvt runs after ctx -> safe.
  f16* w = (f16*)d_ws;
  f16* qh  = w;                          // 0..4MB
  f16* kh  = qh + (size_t)S_LEN * DIM;   // 4..8
  f16* vh  = kh + (size_t)S_LEN * DIM;   // 8..12
  f16* wqh = vh + (size_t)S_LEN * DIM;   // 12..14
  f16* wkh = wqh + (size_t)DIM * DIM;    // 14..16
  f16* wvh = wkh + (size_t)DIM * DIM;    // 16..18
  f16* woh = wvh + (size_t)DIM * DIM;    // 18..20
  f16* Qp  = woh + (size_t)DIM * DIM;    // 20..24
  f16* Kp  = Qp + (size_t)S_LEN * DIM;   // 24..28
  f16* Vt  = Kp + (size_t)S_LEN * DIM;   // 28..32
  f16* IDn = qh;                         // 0..8MB
  float* Cp = (float*)vh;                // 8..16MB
  f16* Ct  = qh;                         // 0..4MB

  const int nqkv4 = S_LEN * DIM / 4, nw4 = DIM * DIM / 4;
  dim3 b256(256);
  cvt3<<<dim3(nqkv4 / 256, 3), b256, 0, stream>>>(q, k, v, qh, kh, vh, nqkv4);
  cvt4<<<dim3(nw4 / 256, 4), b256, 0, stream>>>(Wq, Wk, Wv, Wo, wqh, wkh, wvh, woh, nw4);

  gemm_qkv<<<dim3(DIM / 64, S_LEN / 128, 3), b256, 0, stream>>>(
      qh, kh, vh, wqh, wkh, wvh, bq, bk, bv, Qp, Kp, Vt);

  hipMemsetAsync(Cp, 0, (size_t)S_LEN * DIM * sizeof(float), stream);
  hipMemsetAsync(out, 0, (size_t)S_LEN * DIM * sizeof(float), stream);

  attn_denom<<<dim3(S_LEN / 64, S_LEN / 64), b256, 0, stream>>>(Qp, Kp, IDn);
  attn_ctx<<<dim3(S_LEN / 128, NH, 4), b256, 0, stream>>>(Qp, Kp, Vt, IDn, Cp);

  cvt_f32_f16<<<nqkv4 / 256, b256, 0, stream>>>(Cp, Ct, nqkv4);

  gemm_out<<<dim3(DIM / 64, S_LEN / 128, 2), b256, 0, stream>>>(Ct, woh, bo, out);
}

// Round 5
// 233.331 us; speedup vs baseline: 1.7229x; 1.0089x over previous
//
#include <hip/hip_runtime.h>
#include <hip/hip_fp16.h>

// MHA with softmax over HEADS axis. R5: halve barrier counts (drain amortization).
// - gemm64_core: BK=64 per barrier period (2x 32-col LDS slices, 64B rows)
// - attn_denom: 2 heads per barrier period
// - attn_ctx: 64-j barrier period, two 32-j sub-iters, wave-private Pl reuse
// - all fp32->f16 input conversions merged into one dispatch

typedef _Float16 f16;
typedef _Float16 f16x4 __attribute__((ext_vector_type(4)));
typedef _Float16 f16x8 __attribute__((ext_vector_type(8)));
typedef float    f32x4 __attribute__((ext_vector_type(4)));

#define S_LEN 2048
#define DIM   1024
#define NH    16
#define DK    64
#define SCALE 0.125f

#define MFMA(a, b, c) __builtin_amdgcn_mfma_f32_16x16x32_f16(a, b, c, 0, 0, 0)

typedef __attribute__((address_space(1))) void g_void;
typedef __attribute__((address_space(3))) void l_void;

static __device__ __forceinline__ void gload_lds16(const void* g, void* l) {
  // async global->LDS DMA; dst = wave-uniform base + lane*16 (1KB/inst)
  __builtin_amdgcn_global_load_lds((g_void*)g, (l_void*)l, 16, 0, 0);
}

// ---------------------------------------------------------------- merged cvt fp32->f16
// 10 segments of 1M elements: q(2), k(2), v(2), Wq, Wk, Wv, Wo
__global__ __launch_bounds__(256) void cvt_all(
    const float* __restrict__ q, const float* __restrict__ k, const float* __restrict__ v,
    const float* __restrict__ Wq, const float* __restrict__ Wk, const float* __restrict__ Wv,
    const float* __restrict__ Wo, f16* __restrict__ qh, f16* __restrict__ kh,
    f16* __restrict__ vh, f16* __restrict__ wqh, f16* __restrict__ wkh,
    f16* __restrict__ wvh, f16* __restrict__ woh) {
  const size_t M = 1048576;
  const int seg = blockIdx.y;
  const float* src;
  f16* dst;
  switch (seg) {
    case 0: src = q;      dst = qh;      break;
    case 1: src = q + M;  dst = qh + M;  break;
    case 2: src = k;      dst = kh;      break;
    case 3: src = k + M;  dst = kh + M;  break;
    case 4: src = v;      dst = vh;      break;
    case 5: src = v + M;  dst = vh + M;  break;
    case 6: src = Wq;     dst = wqh;     break;
    case 7: src = Wk;     dst = wkh;     break;
    case 8: src = Wv;     dst = wvh;     break;
    default: src = Wo;    dst = woh;     break;
  }
  int i = blockIdx.x * 256 + threadIdx.x;  // < 262144
  float4 vv = ((const float4*)src)[i];
  f16x4 o = {(f16)vv.x, (f16)vv.y, (f16)vv.z, (f16)vv.w};
  ((f16x4*)dst)[i] = o;
}

__global__ __launch_bounds__(256) void cvt_f32_f16(const float* __restrict__ src,
                                                   f16* __restrict__ dst, int n4) {
  int i = blockIdx.x * 256 + threadIdx.x;
  if (i < n4) {
    float4 v = ((const float4*)src)[i];
    f16x4 o = {(f16)v.x, (f16)v.y, (f16)v.z, (f16)v.w};
    ((f16x4*)dst)[i] = o;
  }
}

// ---------------------------------------------------------------- 128x64 GEMM core, BK=64
// X:(M,1024), W:(N,1024) row-major f16. 4 waves 2x2, wave tile 64x32.
// LDS: As2[2][128][32] + Bs2[2][64][32] = 24KB. 16 MFMA/wave per barrier period.
static __device__ __forceinline__ void gemm64_core(const f16* __restrict__ X,
                                                   const f16* __restrict__ W,
                                                   int k0, int k1, int bm, int bn,
                                                   f16* As2, f16* Bs2,
                                                   f32x4 (&acc)[4][2]) {
  const int tid = threadIdx.x;
  const int wv = tid >> 6;
  const int lane = tid & 63;
  const int qd = lane >> 4;
  const int l16 = lane & 15;
  const int wm = (wv & 1) * 64;
  const int wn = (wv >> 1) * 32;
  const int lr4 = lane >> 2, lc4 = lane & 3;
  const int kkw = wv & 1;         // staged k-slice
  const int rgw = wv >> 1;        // staged row half

  const f16* gA = X + (size_t)(bm + rgw * 64 + lr4) * DIM + k0 + kkw * 32 + lc4 * 8;
  const f16* gB = W + (size_t)(bn + rgw * 32 + lr4) * DIM + k0 + kkw * 32 + lc4 * 8;
  f16* lA = As2 + kkw * (128 * 32) + (rgw * 64) * 32;
  f16* lB = Bs2 + kkw * (64 * 32) + (rgw * 32) * 32;

  for (int kt = k0; kt < k1; kt += 64) {
#pragma unroll
    for (int t = 0; t < 4; t++)
      gload_lds16(gA + t * 16 * DIM, lA + t * 16 * 32);
#pragma unroll
    for (int t = 0; t < 2; t++)
      gload_lds16(gB + t * 16 * DIM, lB + t * 16 * 32);
    gA += 64;
    gB += 64;
    __syncthreads();

    f16x8 af[4][2], bf[2][2];
#pragma unroll
    for (int mi = 0; mi < 4; mi++)
#pragma unroll
      for (int kk = 0; kk < 2; kk++)
        af[mi][kk] = *(const f16x8*)&As2[kk * (128 * 32) + (wm + mi * 16 + l16) * 32 + qd * 8];
#pragma unroll
    for (int ni = 0; ni < 2; ni++)
#pragma unroll
      for (int kk = 0; kk < 2; kk++)
        bf[ni][kk] = *(const f16x8*)&Bs2[kk * (64 * 32) + (wn + ni * 16 + l16) * 32 + qd * 8];
#pragma unroll
    for (int mi = 0; mi < 4; mi++)
#pragma unroll
      for (int ni = 0; ni < 2; ni++) {
        acc[mi][ni] = MFMA(af[mi][0], bf[ni][0], acc[mi][ni]);
        acc[mi][ni] = MFMA(af[mi][1], bf[ni][1], acc[mi][ni]);
      }
    __syncthreads();
  }
}

// ---------------------------------------------------------------- merged QKV proj
// grid (DIM/64, S/128, 3). z=0: Qp; z=1: Kp; z=2: Vt (transposed)
__global__ __launch_bounds__(256) void gemm_qkv(
    const f16* __restrict__ X0, const f16* __restrict__ X1, const f16* __restrict__ X2,
    const f16* __restrict__ W0, const f16* __restrict__ W1, const f16* __restrict__ W2,
    const float* __restrict__ b0, const float* __restrict__ b1, const float* __restrict__ b2,
    f16* __restrict__ o0, f16* __restrict__ o1, f16* __restrict__ o2) {
  __shared__ __align__(16) f16 As2[2 * 128 * 32];
  __shared__ __align__(16) f16 Bs2[2 * 64 * 32];
  const int z = blockIdx.z;
  const f16* X = z == 0 ? X0 : z == 1 ? X1 : X2;
  const f16* W = z == 0 ? W0 : z == 1 ? W1 : W2;
  const float* bias = z == 0 ? b0 : z == 1 ? b1 : b2;
  f16* outh = z == 0 ? o0 : z == 1 ? o1 : o2;

  const int bm = blockIdx.y * 128, bn = blockIdx.x * 64;
  f32x4 acc[4][2];
#pragma unroll
  for (int a = 0; a < 4; a++)
#pragma unroll
    for (int b = 0; b < 2; b++) acc[a][b] = (f32x4){0.f, 0.f, 0.f, 0.f};

  gemm64_core(X, W, 0, DIM, bm, bn, As2, Bs2, acc);

  const int tid = threadIdx.x;
  const int wv = tid >> 6, lane = tid & 63;
  const int qd = lane >> 4, l16 = lane & 15;
  const int wm = (wv & 1) * 64, wn = (wv >> 1) * 32;
#pragma unroll
  for (int mi = 0; mi < 4; mi++) {
#pragma unroll
    for (int ni = 0; ni < 2; ni++) {
      const int gm = bm + wm + mi * 16 + qd * 4;
      const int gn = bn + wn + ni * 16 + l16;
      const float bs = bias[gn];
      if (z == 2) {
        f16x4 o = {(f16)(acc[mi][ni][0] + bs), (f16)(acc[mi][ni][1] + bs),
                   (f16)(acc[mi][ni][2] + bs), (f16)(acc[mi][ni][3] + bs)};
        *(f16x4*)&outh[(size_t)gn * S_LEN + gm] = o;  // Vt[d][j]
      } else {
#pragma unroll
        for (int r = 0; r < 4; r++)
          outh[(size_t)(gm + r) * DIM + gn] = (f16)(acc[mi][ni][r] + bs);
      }
    }
  }
}

// ---------------------------------------------------------------- out GEMM 128x64, splitK2
__global__ __launch_bounds__(256) void gemm_out(const f16* __restrict__ X,
                                                const f16* __restrict__ W,
                                                const float* __restrict__ bias,
                                                float* __restrict__ outf) {
  __shared__ __align__(16) f16 As2[2 * 128 * 32];
  __shared__ __align__(16) f16 Bs2[2 * 64 * 32];
  const int z = blockIdx.z;
  const int bm = blockIdx.y * 128, bn = blockIdx.x * 64;
  f32x4 acc[4][2];
#pragma unroll
  for (int a = 0; a < 4; a++)
#pragma unroll
    for (int b = 0; b < 2; b++) acc[a][b] = (f32x4){0.f, 0.f, 0.f, 0.f};

  gemm64_core(X, W, z * (DIM / 2), (z + 1) * (DIM / 2), bm, bn, As2, Bs2, acc);

  const int tid = threadIdx.x;
  const int wv = tid >> 6, lane = tid & 63;
  const int qd = lane >> 4, l16 = lane & 15;
  const int wm = (wv & 1) * 64, wn = (wv >> 1) * 32;
#pragma unroll
  for (int mi = 0; mi < 4; mi++) {
#pragma unroll
    for (int ni = 0; ni < 2; ni++) {
      const int gm = bm + wm + mi * 16 + qd * 4;
      const int gn = bn + wn + ni * 16 + l16;
      const float bs = z == 0 ? bias[gn] : 0.f;
#pragma unroll
      for (int r = 0; r < 4; r++)
        atomicAdd(&outf[(size_t)(gm + r) * DIM + gn], acc[mi][ni][r] + bs);
    }
  }
}

// ---------------------------------------------------------------- pass A: IDn = 1/sum_h exp
// 64x64 tile per block, grid (S/64, S/64) = 1024. 2 heads per barrier period
// (Qs/Ks[2h][2kk][64][32] = 32KB LDS). dsum per-lane in registers.
__global__ __launch_bounds__(256) void attn_denom(const f16* __restrict__ Qp,
                                                  const f16* __restrict__ Kp,
                                                  f16* __restrict__ IDn) {
  __shared__ __align__(16) f16 Qs[2][2][64 * 32];
  __shared__ __align__(16) f16 Ks[2][2][64 * 32];
  const int tid = threadIdx.x;
  const int wv = tid >> 6;
  const int lane = tid & 63;
  const int qd = lane >> 4;
  const int l16 = lane & 15;
  const int wm = (wv & 1) * 32, wn = (wv >> 1) * 32;
  const int bi = blockIdx.y * 64, bj = blockIdx.x * 64;
  const int lr4 = lane >> 2, lc4 = lane & 3;
  const int hhw = wv & 1;   // staging: wave's head-within-pair
  const int kkw = wv >> 1;  // staging: wave's kk slice

  f32x4 dsum[2][2];
#pragma unroll
  for (int a = 0; a < 2; a++)
#pragma unroll
    for (int b = 0; b < 2; b++) dsum[a][b] = (f32x4){0.f, 0.f, 0.f, 0.f};

  for (int h0 = 0; h0 < NH; h0 += 2) {
    const int hcol = (h0 + hhw) * DK + kkw * 32;
    const f16* gq = Qp + (size_t)(bi + lr4) * DIM + hcol + lc4 * 8;
    const f16* gk = Kp + (size_t)(bj + lr4) * DIM + hcol + lc4 * 8;
#pragma unroll
    for (int t = 0; t < 4; t++) {
      gload_lds16(gq + (size_t)t * 16 * DIM, &Qs[hhw][kkw][t * 16 * 32]);
      gload_lds16(gk + (size_t)t * 16 * DIM, &Ks[hhw][kkw][t * 16 * 32]);
    }
    __syncthreads();

#pragma unroll
    for (int hh = 0; hh < 2; hh++) {
      f16x8 af[2][2], bf[2][2];
#pragma unroll
      for (int mi = 0; mi < 2; mi++)
#pragma unroll
        for (int kk = 0; kk < 2; kk++)
          af[mi][kk] = *(const f16x8*)&Qs[hh][kk][(wm + mi * 16 + l16) * 32 + qd * 8];
#pragma unroll
      for (int ni = 0; ni < 2; ni++)
#pragma unroll
        for (int kk = 0; kk < 2; kk++)
          bf[ni][kk] = *(const f16x8*)&Ks[hh][kk][(wn + ni * 16 + l16) * 32 + qd * 8];
#pragma unroll
      for (int mi = 0; mi < 2; mi++)
#pragma unroll
        for (int ni = 0; ni < 2; ni++) {
          f32x4 s = {0.f, 0.f, 0.f, 0.f};
          s = MFMA(af[mi][0], bf[ni][0], s);  // kk order identical to attn_ctx
          s = MFMA(af[mi][1], bf[ni][1], s);
#pragma unroll
          for (int r = 0; r < 4; r++) dsum[mi][ni][r] += __expf(s[r] * SCALE);
        }
    }
    __syncthreads();
  }
#pragma unroll
  for (int mi = 0; mi < 2; mi++)
#pragma unroll
    for (int ni = 0; ni < 2; ni++)
#pragma unroll
      for (int r = 0; r < 4; r++) {
        const int gi = bi + wm + mi * 16 + qd * 4 + r;
        const int gj = bj + wn + ni * 16 + l16;
        IDn[(size_t)gi * S_LEN + gj] = (f16)(1.f / dsum[mi][ni][r]);
      }
}

// ---------------------------------------------------------------- pass B: ctx
// grid (S/128, NH, 4). Block: i-tile 128, one head, j-range 512, barrier period
// = 64 j (two 32-j sub-iters, Pl reused wave-privately). LDS 40KB -> 4 blocks/CU.
__global__ __launch_bounds__(256) void attn_ctx(const f16* __restrict__ Qp,
                                                const f16* __restrict__ Kp,
                                                const f16* __restrict__ Vt,
                                                const f16* __restrict__ IDn,
                                                float* __restrict__ Cp) {
  __shared__ __align__(16) f16 Ks[2][64 * 32];   // [kk][j64][k32]
  __shared__ __align__(16) f16 Vs[2][64 * 32];   // [sub][d64][j32]
  __shared__ __align__(16) f16 Is[2][128 * 32];  // [sub][i128][j32]
  __shared__ __align__(16) f16 Pl[4][32 * 32];   // per-wave P scratch
  const int tid = threadIdx.x;
  const int wv = tid >> 6;
  const int lane = tid & 63;
  const int qd = lane >> 4;
  const int l16 = lane & 15;
  const int h = blockIdx.y;
  const int i0 = blockIdx.x * 128;
  const int iw = i0 + wv * 32;
  const int jb = blockIdx.z * 512;
  const int lr4 = lane >> 2, lc4 = lane & 3;
  const int sw = wv & 1;    // staging: wave's sub/kk slice
  const int gw = wv >> 1;   // staging: wave's row-group half
  f16* pl = Pl[wv];

  // persistent Q A-frags (loaded once, amortized over 8 periods)
  f16x8 aq[2][2];
#pragma unroll
  for (int mi = 0; mi < 2; mi++)
#pragma unroll
    for (int kk = 0; kk < 2; kk++)
      aq[mi][kk] = *(const f16x8*)(Qp + (size_t)(iw + mi * 16 + l16) * DIM +
                                   h * DK + kk * 32 + qd * 8);

  f32x4 acc[2][4];
#pragma unroll
  for (int a = 0; a < 2; a++)
#pragma unroll
    for (int b = 0; b < 4; b++) acc[a][b] = (f32x4){0.f, 0.f, 0.f, 0.f};

  for (int jt = 0; jt < 8; jt++) {
    const int j0 = jb + jt * 64;
    // ---- stage 32KB/block: 8 DMA per wave
    // K: kk = sw, j-rows gw*32 + t*16 (t=0,1)
#pragma unroll
    for (int t = 0; t < 2; t++)
      gload_lds16(Kp + (size_t)(j0 + gw * 32 + t * 16 + lr4) * DIM + h * DK + sw * 32 + lc4 * 8,
                  &Ks[sw][(gw * 32 + t * 16) * 32]);
    // V: sub = sw, d-rows gw*32 + t*16
#pragma unroll
    for (int t = 0; t < 2; t++)
      gload_lds16(Vt + (size_t)(h * DK + gw * 32 + t * 16 + lr4) * S_LEN + j0 + sw * 32 + lc4 * 8,
                  &Vs[sw][(gw * 32 + t * 16) * 32]);
    // IDn: sub = sw, i-rows gw*64 + t*16 (t=0..3)
#pragma unroll
    for (int t = 0; t < 4; t++)
      gload_lds16(IDn + (size_t)(i0 + gw * 64 + t * 16 + lr4) * S_LEN + j0 + sw * 32 + lc4 * 8,
                  &Is[sw][(gw * 64 + t * 16) * 32]);
    __syncthreads();

#pragma unroll
    for (int sub = 0; sub < 2; sub++) {
      // ---- QK^T -> exp -> Pl (C-layout)
      f16x8 bk[2][2];
#pragma unroll
      for (int ni = 0; ni < 2; ni++)
#pragma unroll
        for (int kk = 0; kk < 2; kk++)
          bk[ni][kk] = *(const f16x8*)&Ks[kk][(sub * 32 + ni * 16 + l16) * 32 + qd * 8];
#pragma unroll
      for (int mi = 0; mi < 2; mi++)
#pragma unroll
        for (int ni = 0; ni < 2; ni++) {
          f32x4 s = {0.f, 0.f, 0.f, 0.f};
          s = MFMA(aq[mi][0], bk[ni][0], s);  // same order as attn_denom
          s = MFMA(aq[mi][1], bk[ni][1], s);
#pragma unroll
          for (int r = 0; r < 4; r++)
            pl[(mi * 16 + qd * 4 + r) * 32 + ni * 16 + l16] = (f16)__expf(s[r] * SCALE);
        }

      // ---- P(A-layout) * IDn, then PV
      f16x8 bv[4];
#pragma unroll
      for (int nd = 0; nd < 4; nd++)
        bv[nd] = *(const f16x8*)&Vs[sub][(nd * 16 + l16) * 32 + qd * 8];
#pragma unroll
      for (int mi = 0; mi < 2; mi++) {
        f16x8 ef = *(const f16x8*)&pl[(mi * 16 + l16) * 32 + qd * 8];  // wave-private
        f16x8 idn = *(const f16x8*)&Is[sub][(wv * 32 + mi * 16 + l16) * 32 + qd * 8];
        f16x8 p = ef * idn;
#pragma unroll
        for (int nd = 0; nd < 4; nd++)
          acc[mi][nd] = MFMA(p, bv[nd], acc[mi][nd]);
      }
    }
    __syncthreads();
  }

#pragma unroll
  for (int mi = 0; mi < 2; mi++)
#pragma unroll
    for (int nd = 0; nd < 4; nd++)
#pragma unroll
      for (int r = 0; r < 4; r++)
        atomicAdd(&Cp[(size_t)(iw + mi * 16 + qd * 4 + r) * DIM + h * DK + nd * 16 + l16],
                  acc[mi][nd][r]);
}

// ---------------------------------------------------------------- launcher
extern "C" void kernel_launch(void* const* d_in, const int* in_sizes, int n_in,
                              void* d_out, int out_size, void* d_ws, size_t ws_size,
                              hipStream_t stream) {
  const float* q  = (const float*)d_in[0];
  const float* k  = (const float*)d_in[1];
  const float* v  = (const float*)d_in[2];
  const float* Wq = (const float*)d_in[3];
  const float* bq = (const float*)d_in[4];
  const float* Wk = (const float*)d_in[5];
  const float* bk = (const float*)d_in[6];
  const float* Wv = (const float*)d_in[7];
  const float* bv = (const float*)d_in[8];
  const float* Wo = (const float*)d_in[9];
  const float* bo = (const float*)d_in[10];
  float* out = (float*)d_out;

  // ws layout (32 MB). Aliases (stream-ordered): IDn over qh+kh [dead after
  // gemm_qkv]; Cp (fp32) over vh+wqh+wkh [dead after gemm_qkv]; Ct over qh
  // [IDn dead after attn_ctx; cvt runs after ctx]. woh NOT aliased.
  f16* w = (f16*)d_ws;
  f16* qh  = w;                          // 0..4MB
  f16* kh  = qh + (size_t)S_LEN * DIM;   // 4..8
  f16* vh  = kh + (size_t)S_LEN * DIM;   // 8..12
  f16* wqh = vh + (size_t)S_LEN * DIM;   // 12..14
  f16* wkh = wqh + (size_t)DIM * DIM;    // 14..16
  f16* wvh = wkh + (size_t)DIM * DIM;    // 16..18
  f16* woh = wvh + (size_t)DIM * DIM;    // 18..20
  f16* Qp  = woh + (size_t)DIM * DIM;    // 20..24
  f16* Kp  = Qp + (size_t)S_LEN * DIM;   // 24..28
  f16* Vt  = Kp + (size_t)S_LEN * DIM;   // 28..32
  f16* IDn = qh;                         // 0..8MB
  float* Cp = (float*)vh;                // 8..16MB
  f16* Ct  = qh;                         // 0..4MB

  dim3 b256(256);
  cvt_all<<<dim3(1024, 10), b256, 0, stream>>>(q, k, v, Wq, Wk, Wv, Wo,
                                               qh, kh, vh, wqh, wkh, wvh, woh);

  gemm_qkv<<<dim3(DIM / 64, S_LEN / 128, 3), b256, 0, stream>>>(
      qh, kh, vh, wqh, wkh, wvh, bq, bk, bv, Qp, Kp, Vt);

  hipMemsetAsync(Cp, 0, (size_t)S_LEN * DIM * sizeof(float), stream);
  hipMemsetAsync(out, 0, (size_t)S_LEN * DIM * sizeof(float), stream);

  attn_denom<<<dim3(S_LEN / 64, S_LEN / 64), b256, 0, stream>>>(Qp, Kp, IDn);
  attn_ctx<<<dim3(S_LEN / 128, NH, 4), b256, 0, stream>>>(Qp, Kp, Vt, IDn, Cp);

  const int nqkv4 = S_LEN * DIM / 4;
  cvt_f32_f16<<<nqkv4 / 256, b256, 0, stream>>>(Cp, Ct, nqkv4);

  gemm_out<<<dim3(DIM / 64, S_LEN / 128, 2), b256, 0, stream>>>(Ct, woh, bo, out);
}